// Round 1
// baseline (1010.193 us; speedup 1.0000x reference)
//
#include <hip/hip_runtime.h>

typedef __attribute__((ext_vector_type(8))) short short8v;
typedef __attribute__((ext_vector_type(4))) float f32x4;
typedef __attribute__((ext_vector_type(4))) unsigned int uint4v;
typedef unsigned short u16;

__device__ __forceinline__ u16 f2bf(float f) {
  unsigned u = __float_as_uint(f);
  u += 0x7FFFu + ((u >> 16) & 1u);
  return (u16)(u >> 16);
}

__device__ __forceinline__ short8v ld8(const u16* p) {
  return *reinterpret_cast<const short8v*>(p);
}

// ---------------- weight packing: fp32 NCHW-kernels -> bf16 MFMA-B layout ----
// Wh*p / Wx1p: [shift s=ky*3+kx][co=128][ci=32], ci contiguous (B-frag: 8 ci / lane)
// Wx0p / Wxdp: [co=128][k=32] im2col layout, k=(ky*3+kx)*3+ci for k<27, else 0
__global__ void k_pack(const float* __restrict__ We0, const float* __restrict__ We1,
                       const float* __restrict__ Wd,
                       u16* __restrict__ Wh0p, u16* __restrict__ Wx0p,
                       u16* __restrict__ Wx1p, u16* __restrict__ Wh1p,
                       u16* __restrict__ Whdp, u16* __restrict__ Wxdp) {
  int i = blockIdx.x * 256 + threadIdx.x;   // total 155648
  if (i < 36864) {
    int s = i >> 12, co = (i >> 5) & 127, ci = i & 31;
    Wh0p[i] = f2bf(We0[(co * 35 + 3 + ci) * 9 + s]);
  } else if (i < 40960) {
    int j = i - 36864; int co = j >> 5, k = j & 31;
    Wx0p[j] = (k < 27) ? f2bf(We0[(co * 35 + (k % 3)) * 9 + (k / 3)]) : (u16)0;
  } else if (i < 77824) {
    int j = i - 40960; int s = j >> 12, co = (j >> 5) & 127, ci = j & 31;
    Wx1p[j] = f2bf(We1[(co * 64 + ci) * 9 + s]);
  } else if (i < 114688) {
    int j = i - 77824; int s = j >> 12, co = (j >> 5) & 127, ci = j & 31;
    Wh1p[j] = f2bf(We1[(co * 64 + 32 + ci) * 9 + s]);
  } else if (i < 151552) {
    int j = i - 114688; int s = j >> 12, co = (j >> 5) & 127, ci = j & 31;
    Whdp[j] = f2bf(Wd[(co * 35 + 3 + ci) * 9 + s]);
  } else if (i < 155648) {
    int j = i - 151552; int co = j >> 5, k = j & 31;
    Wxdp[j] = (k < 27) ? f2bf(Wd[(co * 35 + (k % 3)) * 9 + (k / 3)]) : (u16)0;
  }
}

// ---------------- im2col of x for ALL frames: [t][b][y][x][32] bf16 ----------
__global__ void k_im2col(const float* __restrict__ x, u16* __restrict__ out) {
  int p = blockIdx.x * 256 + threadIdx.x;   // 786432 = 24*8*4096
  int t = p >> 15;
  int rem = p & 32767;
  int b = rem >> 12;
  int yy = (rem >> 6) & 63;
  int xx = rem & 63;
  __align__(16) u16 buf[32];
#pragma unroll
  for (int k = 27; k < 32; k++) buf[k] = 0;
  const float* xb = x + ((size_t)(b * 24 + t)) * 3 * 4096;
#pragma unroll
  for (int ky = 0; ky < 3; ky++) {
    int ys = yy + ky - 1;
    bool yok = (unsigned)ys < 64u;
#pragma unroll
    for (int kx = 0; kx < 3; kx++) {
      int xs = xx + kx - 1;
      bool ok = yok && ((unsigned)xs < 64u);
#pragma unroll
      for (int ci = 0; ci < 3; ci++) {
        float v = ok ? xb[(size_t)ci * 4096 + ys * 64 + xs] : 0.f;
        buf[(ky * 3 + kx) * 3 + ci] = f2bf(v);
      }
    }
  }
  uint4v* dst = (uint4v*)(out + (size_t)p * 32);
  const uint4v* s = (const uint4v*)buf;
  dst[0] = s[0]; dst[1] = s[1]; dst[2] = s[2]; dst[3] = s[3];
}

__global__ void k_zero(uint4v* __restrict__ p, int n) {
  int i = blockIdx.x * 256 + threadIdx.x;
  if (i < n) p[i] = (uint4v)0u;
}

// ---------------- fused ConvLSTM step: conv(s) + gates ----------------------
// MODE 0: layer0  (x-part = im2col K=32 GEMM, h-part = 9 shift GEMMs); writes hs0
// MODE 1: layer1  (x-part = 9 shift GEMMs on hs0_t, h-part = 9 shift GEMMs)
// MODE 2: decoder (like MODE 0 but also writes h_dec as NCHW f32 for the FC)
// block = (b,y) row: M-tile = 64 pixels, N = all 128 gate channels. 4 waves,
// wave w owns co in [w*32, w*32+32) (2 MFMA n-tiles). A/B frags straight from
// global (L1/L2-hot), z accumulated in f32, gates via padded LDS tile.
template <int MODE>
__global__ __launch_bounds__(256) void k_step(
    const u16* __restrict__ xA, const u16* __restrict__ Wx,
    const u16* __restrict__ Wh, const float* __restrict__ bias,
    const u16* __restrict__ hprev, const float* __restrict__ cprev,
    u16* __restrict__ hout, float* __restrict__ cout,
    u16* __restrict__ hs0out, float* __restrict__ hdec) {
  __shared__ float zlds[64][132];
  const int tid = threadIdx.x;
  const int b = blockIdx.x >> 6;
  const int y = blockIdx.x & 63;
  const int l = tid & 63;
  const int w = tid >> 6;
  const int lr = l & 15;
  const int g = l >> 4;

  f32x4 acc[4][2];
#pragma unroll
  for (int i = 0; i < 4; i++)
#pragma unroll
    for (int j = 0; j < 2; j++) acc[i][j] = (f32x4)0.f;

  const int coB0 = w * 32 + lr;
  const int coB1 = w * 32 + 16 + lr;

  if (MODE == 0 || MODE == 2) {
    // im2col chunk: A[m][k] with k already padded to 32
    const u16* abase = xA + (size_t)((b << 12) + (y << 6)) * 32 + g * 8;
    short8v B0 = ld8(Wx + (size_t)coB0 * 32 + g * 8);
    short8v B1 = ld8(Wx + (size_t)coB1 * 32 + g * 8);
#pragma unroll
    for (int mt = 0; mt < 4; mt++) {
      short8v A = ld8(abase + (size_t)(mt * 16 + lr) * 32);
      acc[mt][0] = __builtin_amdgcn_mfma_f32_16x16x32_bf16(A, B0, acc[mt][0], 0, 0, 0);
      acc[mt][1] = __builtin_amdgcn_mfma_f32_16x16x32_bf16(A, B1, acc[mt][1], 0, 0, 0);
    }
  }

  auto do_shifts = [&](const u16* __restrict__ src, const u16* __restrict__ W) {
#pragma unroll
    for (int s = 0; s < 9; s++) {
      const int dy = s / 3 - 1, dx = s % 3 - 1;
      const int ys = y + dy;
      if ((unsigned)ys >= 64u) continue;   // SAME padding: whole row is zero
      short8v B0 = ld8(W + ((size_t)(s * 128) + coB0) * 32 + g * 8);
      short8v B1 = ld8(W + ((size_t)(s * 128) + coB1) * 32 + g * 8);
      const u16* rowb = src + (size_t)((b * 64 + ys) * 64) * 32;
#pragma unroll
      for (int mt = 0; mt < 4; mt++) {
        int xs = mt * 16 + lr + dx;
        int xc = min(max(xs, 0), 63);
        short8v A = ld8(rowb + (size_t)xc * 32 + g * 8);
        if (xs != xc) A = (short8v)0;      // x-border zero
        acc[mt][0] = __builtin_amdgcn_mfma_f32_16x16x32_bf16(A, B0, acc[mt][0], 0, 0, 0);
        acc[mt][1] = __builtin_amdgcn_mfma_f32_16x16x32_bf16(A, B1, acc[mt][1], 0, 0, 0);
      }
    }
  };

  if (MODE == 1) do_shifts(xA, Wx);        // layer1 x-part on hs0_t
  do_shifts(hprev, Wh);                    // recurrent part

  // z -> LDS (D layout: row m = mt*16 + g*4 + j, col n = co)
#pragma unroll
  for (int mt = 0; mt < 4; mt++)
#pragma unroll
    for (int nt = 0; nt < 2; nt++) {
      int co = w * 32 + nt * 16 + lr;
#pragma unroll
      for (int j = 0; j < 4; j++) zlds[mt * 16 + g * 4 + j][co] = acc[mt][nt][j];
    }
  __syncthreads();

  // gates: thread -> pixel p = tid>>2, channels ch0..ch0+7
  const int p = tid >> 2;
  const int ch0 = (tid & 3) * 8;
  const size_t base = ((size_t)((b * 64 + y) * 64 + p)) * 32;
  __align__(16) u16 hbuf[8];
#pragma unroll
  for (int j = 0; j < 8; j++) {
    int ch = ch0 + j;
    float zi = zlds[p][ch] + bias[ch];
    float zf = zlds[p][ch + 32] + bias[ch + 32];
    float zo = zlds[p][ch + 64] + bias[ch + 64];
    float zg = zlds[p][ch + 96] + bias[ch + 96];
    float cold = cprev[base + ch];
    float si = 1.f / (1.f + __expf(-zi));
    float sf = 1.f / (1.f + __expf(-zf));
    float so = 1.f / (1.f + __expf(-zo));
    float cn = sf * cold + si * tanhf(zg);
    float hn = so * tanhf(cn);
    cout[base + ch] = cn;
    hbuf[j] = f2bf(hn);
    if (MODE == 2) hdec[((size_t)(b * 32 + ch) * 64 + y) * 64 + p] = hn;
  }
  uint4v hv = *(const uint4v*)hbuf;
  *(uint4v*)(hout + base + ch0) = hv;
  if (MODE == 0) *(uint4v*)(hs0out + base + ch0) = hv;
}

// ---------------- FC head ---------------------------------------------------
// fc1: [8,256] = feat[8,131072] @ w.T ; split-K partials, no atomics.
__global__ __launch_bounds__(256) void k_fc1(const float* __restrict__ w,
                                             const float* __restrict__ feat,
                                             float* __restrict__ partial) {
  int bg = blockIdx.x, ks = blockIdx.y;    // 32 n-groups x 8 k-splits
  int t = threadIdx.x;
  int gsub = t >> 5, r = t & 31;
  int n = bg * 8 + gsub;
  const float* wr = w + (size_t)n * 131072 + (size_t)ks * 16384;
  const float* fb = feat + (size_t)ks * 16384;
  float acc[8];
#pragma unroll
  for (int i = 0; i < 8; i++) acc[i] = 0.f;
  for (int it = 0; it < 128; it++) {
    int k = it * 128 + r * 4;
    f32x4 wv = *(const f32x4*)(wr + k);
#pragma unroll
    for (int bb = 0; bb < 8; bb++) {
      f32x4 fv = *(const f32x4*)(fb + (size_t)bb * 131072 + k);
      acc[bb] += wv[0] * fv[0] + wv[1] * fv[1] + wv[2] * fv[2] + wv[3] * fv[3];
    }
  }
#pragma unroll
  for (int bb = 0; bb < 8; bb++) {
    float v = acc[bb];
#pragma unroll
    for (int m = 16; m >= 1; m >>= 1) v += __shfl_xor(v, m, 32);
    if (r == 0) partial[((size_t)ks * 8 + bb) * 256 + n] = v;
  }
}

__global__ void k_fc1_fin(const float* __restrict__ partial,
                          const float* __restrict__ b1, float* __restrict__ hdn) {
  int i = blockIdx.x * 256 + threadIdx.x;  // 2048
  if (i >= 2048) return;
  int b = i >> 8, n = i & 255;
  float v = b1[n];
#pragma unroll
  for (int ks = 0; ks < 8; ks++) v += partial[((size_t)ks * 8 + b) * 256 + n];
  hdn[i] = fmaxf(v, 0.f);
}

__global__ void k_fc2(const float* __restrict__ hdn, const float* __restrict__ w2,
                      const float* __restrict__ b2, float* __restrict__ out) {
  int i = blockIdx.x * 256 + threadIdx.x;  // 776 = 8*97
  if (i >= 776) return;
  int b = i / 97, m = i % 97;
  const float* h = hdn + b * 256;
  const float* wr = w2 + m * 256;
  float v = b2[m];
  for (int k = 0; k < 256; k++) v += h[k] * wr[k];
  out[i] = v;
}

// ---------------- launcher ---------------------------------------------------
extern "C" void kernel_launch(void* const* d_in, const int* in_sizes, int n_in,
                              void* d_out, int out_size, void* d_ws, size_t ws_size,
                              hipStream_t stream) {
  const float* x   = (const float*)d_in[0];
  const float* We0 = (const float*)d_in[1];
  const float* be0 = (const float*)d_in[2];
  const float* We1 = (const float*)d_in[3];
  const float* be1 = (const float*)d_in[4];
  const float* Wd  = (const float*)d_in[5];
  const float* bd  = (const float*)d_in[6];
  const float* f1w = (const float*)d_in[7];
  const float* f1b = (const float*)d_in[8];
  const float* f2w = (const float*)d_in[9];
  const float* f2b = (const float*)d_in[10];

  char* ws = (char*)d_ws;
  u16*   imc  = (u16*)(ws + 0);            // 50331648 B : im2col(x) all T
  u16*   hs0  = (u16*)(ws + 50331648);     // 50331648 B : layer0 hidden seq
  u16*   h0a  = (u16*)(ws + 100663296);    // 2 MB each: h ping-pong (bf16 NHWC)
  u16*   h0b  = (u16*)(ws + 102760448);
  float* c0   = (float*)(ws + 104857600);  // 4 MB (f32 NHWC, in-place safe)
  u16*   h1a  = (u16*)(ws + 109051904);
  u16*   h1b  = (u16*)(ws + 111149056);
  float* c1   = (float*)(ws + 113246208);
  float* hdec = (float*)(ws + 117440512);  // 4 MB  h_dec NCHW f32 for FC
  float* part = (float*)(ws + 121634816);  // 64 KB fc1 split-K partials
  float* hdn  = (float*)(ws + 121700352);  // 8 KB
  u16*   wp   = (u16*)(ws + 121708544);    // packed bf16 weights
  u16 *Wh0p = wp, *Wx0p = wp + 36864, *Wx1p = wp + 40960, *Wh1p = wp + 77824,
      *Whdp = wp + 114688, *Wxdp = wp + 151552;

  k_pack<<<608, 256, 0, stream>>>(We0, We1, Wd, Wh0p, Wx0p, Wx1p, Wh1p, Whdp, Wxdp);
  k_im2col<<<3072, 256, 0, stream>>>(x, imc);
  // zero h0a..c1 (16 MB contiguous)
  k_zero<<<4096, 256, 0, stream>>>((uint4v*)h0a, 1048576);

  for (int t = 0; t < 24; ++t) {
    const u16* hp = (t & 1) ? h0b : h0a;
    u16* hn = (t & 1) ? h0a : h0b;
    k_step<0><<<512, 256, 0, stream>>>(imc + (size_t)t * 1048576, Wx0p, Wh0p, be0,
                                       hp, c0, hn, c0, hs0 + (size_t)t * 1048576,
                                       nullptr);
  }
  for (int t = 0; t < 24; ++t) {
    const u16* hp = (t & 1) ? h1b : h1a;
    u16* hn = (t & 1) ? h1a : h1b;
    k_step<1><<<512, 256, 0, stream>>>(hs0 + (size_t)t * 1048576, Wx1p, Wh1p, be1,
                                       hp, c1, hn, c1, nullptr, nullptr);
  }
  // decoder: x-part = im2col of last frame; state = (h1 final, c1 final)
  k_step<2><<<512, 256, 0, stream>>>(imc + (size_t)23 * 1048576, Wxdp, Whdp, bd,
                                     h1a, c1, h0a, c0, nullptr, hdec);

  k_fc1<<<dim3(32, 8), 256, 0, stream>>>(f1w, hdec, part);
  k_fc1_fin<<<8, 256, 0, stream>>>(part, f1b, hdn);
  k_fc2<<<4, 256, 0, stream>>>(hdn, f2w, f2b, (float*)d_out);
}

// Round 2
// 521.327 us; speedup vs baseline: 1.9377x; 1.9377x over previous
//
#include <hip/hip_runtime.h>

typedef __attribute__((ext_vector_type(8))) short short8v;
typedef __attribute__((ext_vector_type(4))) float f32x4;
typedef __attribute__((ext_vector_type(4))) unsigned int uint4v;
typedef unsigned short u16;

__device__ __forceinline__ u16 f2bf(float f) {
  unsigned u = __float_as_uint(f);
  u += 0x7FFFu + ((u >> 16) & 1u);
  return (u16)(u >> 16);
}
__device__ __forceinline__ short8v ld8(const u16* p) {
  return *reinterpret_cast<const short8v*>(p);
}
__device__ __forceinline__ float fsig(float x) { return 1.f / (1.f + __expf(-x)); }
__device__ __forceinline__ float ftanh(float x) {
  float e = __expf(2.f * x);
  return 1.f - 2.f / (e + 1.f);
}

// ---------------- weight packing (unchanged, correct in round 1) -------------
__global__ void k_pack(const float* __restrict__ We0, const float* __restrict__ We1,
                       const float* __restrict__ Wd,
                       u16* __restrict__ Wh0p, u16* __restrict__ Wx0p,
                       u16* __restrict__ Wx1p, u16* __restrict__ Wh1p,
                       u16* __restrict__ Whdp, u16* __restrict__ Wxdp) {
  int i = blockIdx.x * 256 + threadIdx.x;   // total 155648
  if (i < 36864) {
    int s = i >> 12, co = (i >> 5) & 127, ci = i & 31;
    Wh0p[i] = f2bf(We0[(co * 35 + 3 + ci) * 9 + s]);
  } else if (i < 40960) {
    int j = i - 36864; int co = j >> 5, k = j & 31;
    Wx0p[j] = (k < 27) ? f2bf(We0[(co * 35 + (k % 3)) * 9 + (k / 3)]) : (u16)0;
  } else if (i < 77824) {
    int j = i - 40960; int s = j >> 12, co = (j >> 5) & 127, ci = j & 31;
    Wx1p[j] = f2bf(We1[(co * 64 + ci) * 9 + s]);
  } else if (i < 114688) {
    int j = i - 77824; int s = j >> 12, co = (j >> 5) & 127, ci = j & 31;
    Wh1p[j] = f2bf(We1[(co * 64 + 32 + ci) * 9 + s]);
  } else if (i < 151552) {
    int j = i - 114688; int s = j >> 12, co = (j >> 5) & 127, ci = j & 31;
    Whdp[j] = f2bf(Wd[(co * 35 + 3 + ci) * 9 + s]);
  } else if (i < 155648) {
    int j = i - 151552; int co = j >> 5, k = j & 31;
    Wxdp[j] = (k < 27) ? f2bf(Wd[(co * 35 + (k % 3)) * 9 + (k / 3)]) : (u16)0;
  }
}

// ---------------- im2col of x for ALL frames: [t][b][y][x][32] bf16 ----------
__global__ void k_im2col(const float* __restrict__ x, u16* __restrict__ out) {
  int p = blockIdx.x * 256 + threadIdx.x;   // 786432 = 24*8*4096
  int t = p >> 15;
  int rem = p & 32767;
  int b = rem >> 12;
  int yy = (rem >> 6) & 63;
  int xx = rem & 63;
  __align__(16) u16 buf[32];
#pragma unroll
  for (int k = 27; k < 32; k++) buf[k] = 0;
  const float* xb = x + ((size_t)(b * 24 + t)) * 3 * 4096;
#pragma unroll
  for (int ky = 0; ky < 3; ky++) {
    int ys = yy + ky - 1;
    bool yok = (unsigned)ys < 64u;
#pragma unroll
    for (int kx = 0; kx < 3; kx++) {
      int xs = xx + kx - 1;
      bool ok = yok && ((unsigned)xs < 64u);
#pragma unroll
      for (int ci = 0; ci < 3; ci++) {
        float v = ok ? xb[(size_t)ci * 4096 + ys * 64 + xs] : 0.f;
        buf[(ky * 3 + kx) * 3 + ci] = f2bf(v);
      }
    }
  }
  uint4v* dst = (uint4v*)(out + (size_t)p * 32);
  const uint4v* s = (const uint4v*)buf;
  dst[0] = s[0]; dst[1] = s[1]; dst[2] = s[2]; dst[3] = s[3];
}

__global__ void k_zero(uint4v* __restrict__ p, int n) {
  int i = blockIdx.x * 256 + threadIdx.x;
  if (i < n) p[i] = (uint4v)0u;
}

// ---------------- fused ConvLSTM step body ----------------------------------
// MODE 0: layer0 (x-part = im2col K=32 GEMM from global; h staged in LDS)
// MODE 1: layer1 (x-part = 9-shift on staged hs0_t; h staged in LDS)
// MODE 2: decoder (MODE 0 + hdec NCHW f32 output)
// Per block: one (b,y) row, M=64 px, N=128 gate ch. 4 waves split N.
// LDS: staging [op][3][66][32] bf16 (x-padded, zero borders) UNION z [64][132] f32.
template <int MODE>
__device__ __forceinline__ void step_body(
    char* smem, int bid,
    const u16* __restrict__ xA, const u16* __restrict__ Wx,
    const u16* __restrict__ Wh, const float* __restrict__ bias,
    const u16* __restrict__ hprev, const float* __restrict__ cprev,
    u16* __restrict__ hout, float* __restrict__ cout,
    u16* __restrict__ hs0out, float* __restrict__ hdec) {
  const int tid = threadIdx.x;
  const int b = bid >> 6;
  const int y = bid & 63;
  const int l = tid & 63;
  const int w = tid >> 6;
  const int lr = l & 15;
  const int g = l >> 4;

  u16* sm_h = (u16*)smem;                 // [3][66][32] = 12672 B
  u16* sm_x = (u16*)(smem + 12672);       // MODE1 only
  float (*zlds)[132] = (float(*)[132])smem;  // union, used after MFMAs

  // ---- stage rows of hprev (and xA for MODE1) with x-padding --------------
  {
    // zero the 1-px pads on both ends of each row slot
    if (tid < (MODE == 1 ? 48 : 24)) {
      int op = tid >> 5 ? 1 : 0;          // tid 0..23 -> h, 24..47 -> x (MODE1)
      int q = tid - op * 24;
      int r = q >> 3, qq = q & 7;
      u16* base = (op ? sm_x : sm_h) + r * 2112 + ((qq < 4) ? 0 : 65 * 32);
      ((uint4v*)base)[qq & 3] = (uint4v)0u;
    }
#pragma unroll
    for (int i = tid; i < 768; i += 256) {
      int r = i >> 8, j = i & 255;        // j-th uint4 (8 u16) within row
      int ys = y + r - 1;
      uint4v v = (uint4v)0u;
      if ((unsigned)ys < 64u)
        v = *(const uint4v*)(hprev + ((size_t)((b * 64 + ys) * 64)) * 32 + j * 8);
      *(uint4v*)(sm_h + r * 2112 + 32 + j * 8) = v;
      if (MODE == 1) {
        uint4v vx = (uint4v)0u;
        if ((unsigned)ys < 64u)
          vx = *(const uint4v*)(xA + ((size_t)((b * 64 + ys) * 64)) * 32 + j * 8);
        *(uint4v*)(sm_x + r * 2112 + 32 + j * 8) = vx;
      }
    }
  }
  __syncthreads();

  f32x4 acc[4][2];
#pragma unroll
  for (int i = 0; i < 4; i++)
#pragma unroll
    for (int j = 0; j < 2; j++) acc[i][j] = (f32x4)0.f;

  const int coB0 = w * 32 + lr;
  const int coB1 = w * 32 + 16 + lr;

  if (MODE == 0 || MODE == 2) {
    const u16* abase = xA + (size_t)((b << 12) + (y << 6)) * 32 + g * 8;
    short8v B0 = ld8(Wx + (size_t)coB0 * 32 + g * 8);
    short8v B1 = ld8(Wx + (size_t)coB1 * 32 + g * 8);
#pragma unroll
    for (int mt = 0; mt < 4; mt++) {
      short8v A = ld8(abase + (size_t)(mt * 16 + lr) * 32);
      acc[mt][0] = __builtin_amdgcn_mfma_f32_16x16x32_bf16(A, B0, acc[mt][0], 0, 0, 0);
      acc[mt][1] = __builtin_amdgcn_mfma_f32_16x16x32_bf16(A, B1, acc[mt][1], 0, 0, 0);
    }
  }

  auto do_shifts = [&](const u16* sm, const u16* __restrict__ W) {
#pragma unroll
    for (int s = 0; s < 9; s++) {
      const int r = s / 3, dx = s % 3 - 1;
      int ys = y + r - 1;
      if ((unsigned)ys >= 64u) continue;   // block-uniform skip (border rows)
      short8v B0 = ld8(W + ((size_t)(s * 128) + coB0) * 32 + g * 8);
      short8v B1 = ld8(W + ((size_t)(s * 128) + coB1) * 32 + g * 8);
      const u16* base = sm + r * 2112 + (lr + dx + 1) * 32 + g * 8;
#pragma unroll
      for (int mt = 0; mt < 4; mt++) {
        short8v A = ld8(base + mt * 512);  // 16 px * 32 ch
        acc[mt][0] = __builtin_amdgcn_mfma_f32_16x16x32_bf16(A, B0, acc[mt][0], 0, 0, 0);
        acc[mt][1] = __builtin_amdgcn_mfma_f32_16x16x32_bf16(A, B1, acc[mt][1], 0, 0, 0);
      }
    }
  };

  if (MODE == 1) do_shifts(sm_x, Wx);
  do_shifts(sm_h, Wh);

  __syncthreads();   // staging reads done before z overwrites the union
#pragma unroll
  for (int mt = 0; mt < 4; mt++)
#pragma unroll
    for (int nt = 0; nt < 2; nt++) {
      int co = w * 32 + nt * 16 + lr;
#pragma unroll
      for (int j = 0; j < 4; j++) zlds[mt * 16 + g * 4 + j][co] = acc[mt][nt][j];
    }
  __syncthreads();

  // gates: thread -> pixel p = tid>>2, channels ch0..ch0+7
  const int p = tid >> 2;
  const int ch0 = (tid & 3) * 8;
  const size_t base = ((size_t)((b * 64 + y) * 64 + p)) * 32;
  __align__(16) u16 hbuf[8];
#pragma unroll
  for (int j = 0; j < 8; j++) {
    int ch = ch0 + j;
    float zi = zlds[p][ch] + bias[ch];
    float zf = zlds[p][ch + 32] + bias[ch + 32];
    float zo = zlds[p][ch + 64] + bias[ch + 64];
    float zg = zlds[p][ch + 96] + bias[ch + 96];
    float cold = cprev[base + ch];
    float cn = fsig(zf) * cold + fsig(zi) * ftanh(zg);
    float hn = fsig(zo) * ftanh(cn);
    cout[base + ch] = cn;
    hbuf[j] = f2bf(hn);
    if (MODE == 2) hdec[((size_t)(b * 32 + ch) * 64 + y) * 64 + p] = hn;
  }
  uint4v hv = *(const uint4v*)hbuf;
  *(uint4v*)(hout + base + ch0) = hv;
  if (MODE == 0) *(uint4v*)(hs0out + base + ch0) = hv;
}

// dual-layer launch: blocks 0..511 = layer0 step t, 512..1023 = layer1 step t-1
__global__ __launch_bounds__(256, 4) void k_dual(
    int t, const u16* __restrict__ imc, u16* __restrict__ hs0,
    u16* h0a, u16* h0b, float* c0, u16* h1a, u16* h1b, float* c1,
    const u16* __restrict__ Wx0, const u16* __restrict__ Wh0, const float* __restrict__ be0,
    const u16* __restrict__ Wx1, const u16* __restrict__ Wh1, const float* __restrict__ be1) {
  __shared__ __align__(16) char smem[33792];
  int bid = blockIdx.x;
  if (bid < 512) {
    if (t >= 24) return;
    const u16* hp = (t & 1) ? h0b : h0a;
    u16* hn = (t & 1) ? h0a : h0b;
    step_body<0>(smem, bid, imc + (size_t)t * 1048576, Wx0, Wh0, be0, hp, c0, hn,
                 c0, hs0 + (size_t)t * 1048576, nullptr);
  } else {
    int tt = t - 1;
    if (tt < 0) return;
    const u16* hp = (tt & 1) ? h1b : h1a;
    u16* hn = (tt & 1) ? h1a : h1b;
    step_body<1>(smem, bid - 512, hs0 + (size_t)tt * 1048576, Wx1, Wh1, be1, hp,
                 c1, hn, c1, nullptr, nullptr);
  }
}

__global__ __launch_bounds__(256, 4) void k_dec(
    const u16* __restrict__ imc23, const u16* __restrict__ Wxd,
    const u16* __restrict__ Whd, const float* __restrict__ bd,
    const u16* __restrict__ h1fin, const float* __restrict__ c1,
    u16* __restrict__ hscr, float* __restrict__ cscr, float* __restrict__ hdec) {
  __shared__ __align__(16) char smem[33792];
  step_body<2>(smem, blockIdx.x, imc23, Wxd, Whd, bd, h1fin, c1, hscr, cscr,
               nullptr, hdec);
}

// ---------------- FC head ---------------------------------------------------
// fc1: [8,256] = feat[8,131072] @ w.T ; 64 n-groups x 32 k-splits = 2048 blocks
__global__ __launch_bounds__(256) void k_fc1(const float* __restrict__ w,
                                             const float* __restrict__ feat,
                                             float* __restrict__ partial) {
  int bg = blockIdx.x, ks = blockIdx.y;
  int nsub = threadIdx.x >> 6, lane = threadIdx.x & 63;
  int n = bg * 4 + nsub;
  const float* wr = w + (size_t)n * 131072 + (size_t)ks * 4096;
  const float* fb = feat + (size_t)ks * 4096;
  float acc[8];
#pragma unroll
  for (int i = 0; i < 8; i++) acc[i] = 0.f;
#pragma unroll 4
  for (int it = 0; it < 16; it++) {
    int k = it * 256 + lane * 4;
    f32x4 wv = *(const f32x4*)(wr + k);
#pragma unroll
    for (int bb = 0; bb < 8; bb++) {
      f32x4 fv = *(const f32x4*)(fb + (size_t)bb * 131072 + k);
      acc[bb] += wv[0] * fv[0] + wv[1] * fv[1] + wv[2] * fv[2] + wv[3] * fv[3];
    }
  }
#pragma unroll
  for (int bb = 0; bb < 8; bb++) {
    float v = acc[bb];
#pragma unroll
    for (int m = 32; m >= 1; m >>= 1) v += __shfl_xor(v, m, 64);
    if (lane == 0) partial[((size_t)ks * 8 + bb) * 256 + n] = v;
  }
}

__global__ void k_fc1_fin(const float* __restrict__ partial,
                          const float* __restrict__ b1, float* __restrict__ hdn) {
  int i = blockIdx.x * 256 + threadIdx.x;  // 2048
  if (i >= 2048) return;
  int b = i >> 8, n = i & 255;
  float v = b1[n];
#pragma unroll
  for (int ks = 0; ks < 32; ks++) v += partial[((size_t)ks * 8 + b) * 256 + n];
  hdn[i] = fmaxf(v, 0.f);
}

__global__ void k_fc2(const float* __restrict__ hdn, const float* __restrict__ w2,
                      const float* __restrict__ b2, float* __restrict__ out) {
  int i = blockIdx.x * 256 + threadIdx.x;  // 776 = 8*97
  if (i >= 776) return;
  int b = i / 97, m = i % 97;
  const float* h = hdn + b * 256;
  const float* wr = w2 + m * 256;
  float v = b2[m];
  for (int k = 0; k < 256; k++) v += h[k] * wr[k];
  out[i] = v;
}

// ---------------- launcher ---------------------------------------------------
extern "C" void kernel_launch(void* const* d_in, const int* in_sizes, int n_in,
                              void* d_out, int out_size, void* d_ws, size_t ws_size,
                              hipStream_t stream) {
  const float* x   = (const float*)d_in[0];
  const float* We0 = (const float*)d_in[1];
  const float* be0 = (const float*)d_in[2];
  const float* We1 = (const float*)d_in[3];
  const float* be1 = (const float*)d_in[4];
  const float* Wd  = (const float*)d_in[5];
  const float* bd  = (const float*)d_in[6];
  const float* f1w = (const float*)d_in[7];
  const float* f1b = (const float*)d_in[8];
  const float* f2w = (const float*)d_in[9];
  const float* f2b = (const float*)d_in[10];

  char* ws = (char*)d_ws;
  u16*   imc  = (u16*)(ws + 0);            // 50331648 B
  u16*   hs0  = (u16*)(ws + 50331648);     // 50331648 B
  u16*   h0a  = (u16*)(ws + 100663296);
  u16*   h0b  = (u16*)(ws + 102760448);
  float* c0   = (float*)(ws + 104857600);
  u16*   h1a  = (u16*)(ws + 109051904);
  u16*   h1b  = (u16*)(ws + 111149056);
  float* c1   = (float*)(ws + 113246208);
  float* hdec = (float*)(ws + 117440512);  // 4 MB
  float* part = (float*)(ws + 121634816);  // 256 KB (32 ks x 8 b x 256 n)
  float* hdn  = (float*)(ws + 121896960);  // 8 KB
  u16*   wp   = (u16*)(ws + 121905152);    // packed bf16 weights (311296 B)
  u16 *Wh0p = wp, *Wx0p = wp + 36864, *Wx1p = wp + 40960, *Wh1p = wp + 77824,
      *Whdp = wp + 114688, *Wxdp = wp + 151552;

  k_pack<<<608, 256, 0, stream>>>(We0, We1, Wd, Wh0p, Wx0p, Wx1p, Wh1p, Whdp, Wxdp);
  k_im2col<<<3072, 256, 0, stream>>>(x, imc);
  k_zero<<<4096, 256, 0, stream>>>((uint4v*)h0a, 1048576);   // h0a..c1 = 16 MB

  for (int t = 0; t <= 24; ++t)
    k_dual<<<1024, 256, 0, stream>>>(t, imc, hs0, h0a, h0b, c0, h1a, h1b, c1,
                                     Wx0p, Wh0p, be0, Wx1p, Wh1p, be1);

  // layer1 final state: tt=23 (odd) -> written to h1a; c1 in place
  k_dec<<<512, 256, 0, stream>>>(imc + (size_t)23 * 1048576, Wxdp, Whdp, bd,
                                 h1a, c1, h0a, c0, hdec);

  k_fc1<<<dim3(64, 32), 256, 0, stream>>>(f1w, hdec, part);
  k_fc1_fin<<<8, 256, 0, stream>>>(part, f1b, hdn);
  k_fc2<<<4, 256, 0, stream>>>(hdn, f2w, f2b, (float*)d_out);
}